// Round 1
// baseline (461.392 us; speedup 1.0000x reference)
//
#include <hip/hip_runtime.h>
#include <math.h>

// Problem constants (match reference file)
#define BATCH 8192
#define NFEAT 256
#define H1 100
#define H2 50
#define FPB 8    // features per block (each thread loops over 8 features)

// Grid: x = BATCH/256 batch chunks, y = NFEAT/FPB feature groups.
// One thread = one batch row within the chunk, looping over FPB features.
// All weight indices are wave-uniform (blockIdx + unrolled loop constants),
// so weight reads should compile to s_load via the scalar/constant cache,
// leaving the vector pipe for the 5000-FMA fc2 inner product.
__global__ __launch_bounds__(256) void nam_main(
    const float* __restrict__ x,
    const float* __restrict__ W1,
    const float* __restrict__ b1,
    const float* __restrict__ W2,
    const float* __restrict__ b2,
    const float* __restrict__ W3,
    float* __restrict__ acc_out)
{
    const int b  = blockIdx.x * blockDim.x + threadIdx.x; // batch row
    const int f0 = blockIdx.y * FPB;

    float contrib = 0.0f;

    for (int j = 0; j < FPB; ++j) {
        const int f = f0 + j;
        const float xv = x[b * NFEAT + f];

        const float* __restrict__ w1p = W1 + f * H1;
        const float* __restrict__ b1p = b1 + f * H1;

        // fc1: h1[h] = relu(x * W1 + b1), fully unrolled -> h1 in registers
        float h1[H1];
#pragma unroll
        for (int h = 0; h < H1; ++h) {
            h1[h] = fmaxf(0.0f, fmaf(xv, w1p[h], b1p[h]));
        }

        const float* __restrict__ w2p = W2 + (size_t)f * H2 * H1;
        const float* __restrict__ b2p = b2 + f * H2;
        const float* __restrict__ w3p = W3 + f * H2;

        // fc2 + fc3: for each output o, 100-term dot with 4 independent
        // accumulator chains (breaks the 4-cycle FMA latency chain).
        for (int o = 0; o < H2; ++o) {
            const float* __restrict__ w = w2p + o * H1;
            float a0 = b2p[o], a1 = 0.0f, a2 = 0.0f, a3 = 0.0f;
#pragma unroll
            for (int h = 0; h < H1; h += 4) {
                a0 = fmaf(h1[h + 0], w[h + 0], a0);
                a1 = fmaf(h1[h + 1], w[h + 1], a1);
                a2 = fmaf(h1[h + 2], w[h + 2], a2);
                a3 = fmaf(h1[h + 3], w[h + 3], a3);
            }
            const float h2v = fmaxf(0.0f, (a0 + a1) + (a2 + a3));
            contrib = fmaf(h2v, w3p[o], contrib);
        }
    }

    // Per-thread partial over FPB features -> device-scope atomic into d_out.
    atomicAdd(&acc_out[b], contrib);
}

__global__ __launch_bounds__(256) void nam_finish(
    float* __restrict__ out, const float* __restrict__ bias)
{
    const int b = blockIdx.x * blockDim.x + threadIdx.x;
    const float v = out[b] + bias[0];
    out[b] = 1.0f / (1.0f + expf(-v));
}

extern "C" void kernel_launch(void* const* d_in, const int* in_sizes, int n_in,
                              void* d_out, int out_size, void* d_ws, size_t ws_size,
                              hipStream_t stream) {
    const float* x    = (const float*)d_in[0];
    const float* W1   = (const float*)d_in[1];
    const float* b1   = (const float*)d_in[2];
    const float* W2   = (const float*)d_in[3];
    const float* b2   = (const float*)d_in[4];
    const float* W3   = (const float*)d_in[5];
    const float* bias = (const float*)d_in[6];
    float* out = (float*)d_out;

    // d_out is poisoned 0xAA before every timed replay -> zero it ourselves.
    hipMemsetAsync(out, 0, (size_t)BATCH * sizeof(float), stream);

    dim3 grid(BATCH / 256, NFEAT / FPB);
    nam_main<<<grid, 256, 0, stream>>>(x, W1, b1, W2, b2, W3, out);

    nam_finish<<<BATCH / 256, 256, 0, stream>>>(out, bias);
}